// Round 12
// baseline (331.503 us; speedup 1.0000x reference)
//
#include <hip/hip_runtime.h>
#include <hip/hip_bf16.h>
#include <cstdint>
#include <cstddef>

#define B_ 4
#define N_ 4096
#define D_ 1024
#define K_ 256
#define M_ (B_ * N_)          // 16384 rows
#define P_ (6 * K_)           // 1536 proj cols
#define DK2_ (2 * K_)         // 512 rho cols

static __device__ __forceinline__ float sigm(float x) {
    return 1.0f / (1.0f + __expf(-x));
}
static __device__ __forceinline__ float softplusf_(float x) {
    return fmaxf(x, 0.0f) + __logf(1.0f + __expf(-fabsf(x)));
}
static __device__ __forceinline__ unsigned short f2bf(float f) {
    uint32_t u = __float_as_uint(f);
    uint32_t r = (u + 0x7FFFu + ((u >> 16) & 1u)) >> 16;
    return (unsigned short)r;
}

#define GATE_BIAS 0.6190392084062235f
#define AMP_MAX 3.0f

typedef __attribute__((ext_vector_type(8))) __bf16 bf16x8;
typedef __attribute__((ext_vector_type(4))) float f32x4;

// async global->LDS, 16B per lane; lds dest must be wave-uniform base (HW adds lane*16)
static __device__ __forceinline__ void gload_lds16(const unsigned short* g, unsigned short* l) {
    __builtin_amdgcn_global_load_lds(
        (const __attribute__((address_space(1))) void*)g,
        (__attribute__((address_space(3))) void*)l, 16, 0, 0);
}

// ---------------- fp32 -> bf16 convert ----------------
__global__ __launch_bounds__(256) void cvt_kernel(const float* __restrict__ src,
                                                  unsigned short* __restrict__ dst, int n4) {
    int i = blockIdx.x * 256 + threadIdx.x;
    if (i < n4) {
        float4 v = reinterpret_cast<const float4*>(src)[i];
        ushort4 o;
        o.x = f2bf(v.x); o.y = f2bf(v.y); o.z = f2bf(v.z); o.w = f2bf(v.w);
        reinterpret_cast<ushort4*>(dst)[i] = o;
    }
}

// ---------------- bf16 GEMM, C[M][N] = A[M][Kd] * B[N][Kd]^T ----------------
// BK=32, LDS halved -> 2 BLOCKS/CU. 8 waves (2M x 4N), wave tile
// (BM/2) x (BN/4). Relaxed schedule: stage next tile, read frags, MFMA,
// vmcnt(0)+lgkmcnt(0), one barrier per K-tile. Cross-block TLP (4 waves/SIMD
// from 2 resident blocks) hides drain/barrier stalls that pinned all four
// 1-block/CU schedules (r7-r10) at ~4690 cyc/tile.
// LDS row stride = 32 elem = 64 B; swizzle: 16B-slot ^= (row>>1)&3, applied
// on BOTH the pre-swizzled global source and the FRAG read (rule 21):
// physical slot s holds global slot s^((row>>1)&3); FRAG32 reads physical
// ks^((row>>1)&3) -> global ks. Per 16-lane fragment group every bank is
// hit exactly 2x -> conflict-free (2-way is free, m136).

// swizzled fragment read: row r from [rows][32] tile, k-slot ks = lk>>3
#define FRAG32(BUF, r, ks) \
    (*reinterpret_cast<const bf16x8*>(&(BUF)[(size_t)(r) * 32 + ((((ks) ^ (((r) >> 1) & 3))) << 3)]))

template <int BM, int BN, bool ADD_BIAS, bool SCALE, typename OutT>
__global__ __launch_bounds__(512, 4) void gemm_bt(const unsigned short* __restrict__ A,
                                                  const unsigned short* __restrict__ Bm,
                                                  const float* __restrict__ bias,
                                                  const float* __restrict__ scale_p,
                                                  OutT* __restrict__ C, int M, int N, int Kd) {
    constexpr int MR = BM / 32;        // A-frags per wave (8 or 4)
    constexpr int NBF = BN / 64;       // B-frags per wave (3 or 2)
    constexpr int WCOL = BN / 4;       // wave column extent
    __shared__ unsigned short As0[BM * 32];
    __shared__ unsigned short Bs0[BN * 32];
    __shared__ unsigned short As1[BM * 32];
    __shared__ unsigned short Bs1[BN * 32];

    const int tid = threadIdx.x;
    const int w = tid >> 6, l = tid & 63;
    const int m0 = blockIdx.x * BM;
    const int n0 = blockIdx.y * BN;
    const int wm = w >> 2, wn = w & 3;         // 2 x 4 wave grid
    const int lr = l & 15;
    const int ks = l >> 4;                     // k-slot 0..3 (8 elems each)
    const int nt = Kd >> 5;                    // 32 (GEMM1) / 16 (GEMM2), even

    // staging geometry: 4 lanes per 32-elem row; 512 threads cover 128 rows
    const int srow = tid >> 2;                 // 0..127
    const int sslot = tid & 3;
    const int wbase8 = (tid & ~63) * 8;        // wave-uniform LDS elem base

    f32x4 acc[MR][NBF];
#pragma unroll
    for (int mi = 0; mi < MR; ++mi)
#pragma unroll
        for (int ni = 0; ni < NBF; ++ni) acc[mi][ni] = (f32x4){0.f, 0.f, 0.f, 0.f};

#define STAGE_ALL(PA, PB, K0)                                                         \
    {                                                                                 \
        _Pragma("unroll") for (int g = 0; g < BM / 128; ++g) {                        \
            int row = g * 128 + srow;                                                 \
            int col = (K0) + ((sslot ^ ((row >> 1) & 3)) << 3);                       \
            gload_lds16(A + (size_t)(m0 + row) * Kd + col, (PA) + g * 4096 + wbase8); \
        }                                                                             \
        _Pragma("unroll") for (int g = 0; g < BN / 128; ++g) {                        \
            int row = g * 128 + srow;                                                 \
            int col = (K0) + ((sslot ^ ((row >> 1) & 3)) << 3);                       \
            gload_lds16(Bm + (size_t)(n0 + row) * Kd + col, (PB) + g * 4096 + wbase8);\
        }                                                                             \
        if constexpr ((BN % 128) != 0) {                                              \
            if (tid < 256) {                                                          \
                int row = (BN / 128) * 128 + srow;                                    \
                int col = (K0) + ((sslot ^ ((row >> 1) & 3)) << 3);                   \
                gload_lds16(Bm + (size_t)(n0 + row) * Kd + col,                       \
                            (PB) + (BN / 128) * 4096 + wbase8);                       \
            }                                                                         \
        }                                                                             \
    }

#define TILE_STEP(T, CA, CB, PA, PB)                                                  \
    {                                                                                 \
        if ((T) + 1 < nt) STAGE_ALL(PA, PB, ((T) + 1) * 32);                          \
        bf16x8 af[MR], bfr[NBF];                                                      \
        _Pragma("unroll") for (int f = 0; f < MR; ++f) {                              \
            int ar = wm * (BM / 2) + f * 16 + lr;                                     \
            af[f] = FRAG32(CA, ar, ks);                                               \
        }                                                                             \
        _Pragma("unroll") for (int f = 0; f < NBF; ++f) {                             \
            int br = wn * WCOL + f * 16 + lr;                                         \
            bfr[f] = FRAG32(CB, br, ks);                                              \
        }                                                                             \
        __builtin_amdgcn_s_setprio(1);                                                \
        _Pragma("unroll") for (int mi = 0; mi < MR; ++mi)                             \
            _Pragma("unroll") for (int ni = 0; ni < NBF; ++ni)                        \
                acc[mi][ni] = __builtin_amdgcn_mfma_f32_16x16x32_bf16(                \
                    af[mi], bfr[ni], acc[mi][ni], 0, 0, 0);                           \
        __builtin_amdgcn_s_setprio(0);                                                \
        asm volatile("s_waitcnt vmcnt(0) lgkmcnt(0)" ::: "memory");                   \
        __builtin_amdgcn_s_barrier();                                                 \
    }

    // prologue: stage tile 0, drain, barrier
    STAGE_ALL(As0, Bs0, 0);
    asm volatile("s_waitcnt vmcnt(0)" ::: "memory");
    __builtin_amdgcn_s_barrier();

    for (int t = 0; t < nt; t += 2) {
        TILE_STEP(t, As0, Bs0, As1, Bs1);
        TILE_STEP(t + 1, As1, Bs1, As0, Bs0);
    }

    float sc = SCALE ? *scale_p : 1.0f;
#pragma unroll
    for (int mi = 0; mi < MR; ++mi) {
        int row = m0 + wm * (BM / 2) + mi * 16 + (l >> 4) * 4;
#pragma unroll
        for (int ni = 0; ni < NBF; ++ni) {
            int col = n0 + wn * WCOL + ni * 16 + lr;
            float bv = ADD_BIAS ? bias[col] : 0.0f;
#pragma unroll
            for (int j = 0; j < 4; ++j) {
                float v = acc[mi][ni][j] + bv;
                if (SCALE) v *= sc;
                C[(size_t)(row + j) * N + col] = (OutT)v;
            }
        }
    }
#undef STAGE_ALL
#undef TILE_STEP
}

// ---------------- per-step oscillator math (fp16 raw) ----------------
struct Step {
    float alpha, dr, di, cs, sn, g, beta;
};
template <bool FULL>
static __device__ __forceinline__ Step compute_step(const _Float16* __restrict__ p, float pos) {
    Step s;
    float a_raw = (float)p[0];
    float o_raw = (float)p[K_];
    float phi   = (float)p[2 * K_];
    float al    = (float)p[3 * K_];
    float A     = AMP_MAX * sigm(a_raw);
    float omega = softplusf_(o_raw);
    float alpha = sigm(al + GATE_BIAS);
    float angle = omega * pos + phi;
    float sn, cs;
    __sincosf(angle, &sn, &cs);
    float oma = 1.0f - alpha;
    s.alpha = alpha;
    s.dr = oma * A * cs;
    s.di = oma * A * sn;
    s.cs = cs;
    s.sn = sn;
    if (FULL) {
        s.g    = sigm((float)p[4 * K_]);
        s.beta = sigm((float)p[5 * K_]);
    }
    return s;
}

// ---------------- scan stage 1: chunk + sub-chunk summaries ----------------
// grid: (chunk=16, kgroup=16, b=4); block: 256 = 16 channels x 16 sub-chunks of 16 steps
__global__ __launch_bounds__(256) void scan_sum_kernel(const _Float16* __restrict__ raw,
                                                       float* __restrict__ sA,
                                                       float* __restrict__ sR,
                                                       float* __restrict__ sI,
                                                       float* __restrict__ subA,
                                                       float* __restrict__ subR,
                                                       float* __restrict__ subI) {
    const int tid = threadIdx.x;
    const int c = tid & 15, t = tid >> 4;
    const int chunk = blockIdx.x, kg = blockIdx.y, b = blockIdx.z;
    const int k = kg * 16 + c;
    const int n0 = chunk * 256 + t * 16;
    const _Float16* base = raw + (size_t)(b * N_ + n0) * P_ + k;

    float aP = 1.0f, rR = 0.0f, rI = 0.0f;
#pragma unroll
    for (int j = 0; j < 16; ++j) {
        Step s = compute_step<false>(base + (size_t)j * P_, __logf((float)(n0 + j + 1)));
        aP *= s.alpha;
        rR = s.alpha * rR + s.dr;
        rI = s.alpha * rI + s.di;
    }
    // sub-chunk summary -> global (consumed by scan_apply instead of recompute)
    const int chan = b * K_ + kg * 16 + c;
    const int sidx = (chunk * 16 + t) * 1024 + chan;
    subA[sidx] = aP;
    subR[sidx] = rR;
    subI[sidx] = rI;

    __shared__ float lA[256], lR[256], lI[256];
    lA[c * 16 + t] = aP;
    lR[c * 16 + t] = rR;
    lI[c * 16 + t] = rI;
    __syncthreads();
    if (tid < 16) {
        float a = 1.0f, r = 0.0f, im = 0.0f;
        for (int tt = 0; tt < 16; ++tt) {
            float at = lA[tid * 16 + tt];
            r  = at * r  + lR[tid * 16 + tt];
            im = at * im + lI[tid * 16 + tt];
            a *= at;
        }
        int chanw = b * K_ + kg * 16 + tid;
        sA[chunk * 1024 + chanw] = a;
        sR[chunk * 1024 + chanw] = r;
        sI[chunk * 1024 + chanw] = im;
    }
}

// ---------------- scan stage 2: apply + postprocess -> rho (bf16) ----------------
__global__ __launch_bounds__(256) void scan_apply_kernel(const _Float16* __restrict__ raw,
                                                         const float* __restrict__ sA,
                                                         const float* __restrict__ sR,
                                                         const float* __restrict__ sI,
                                                         const float* __restrict__ subA,
                                                         const float* __restrict__ subR,
                                                         const float* __restrict__ subI,
                                                         unsigned short* __restrict__ rho) {
    const int tid = threadIdx.x;
    const int c = tid & 15, t = tid >> 4;
    const int chunk = blockIdx.x, kg = blockIdx.y, b = blockIdx.z;
    const int k = kg * 16 + c;
    const int n0 = chunk * 256 + t * 16;
    const _Float16* base = raw + (size_t)(b * N_ + n0) * P_ + k;

    // chunk-prefix (exclusive) for channel handled by lanes tid<16
    float pR = 0.0f, pI = 0.0f;
    if (tid < 16) {
        int chan = b * K_ + kg * 16 + tid;
        for (int ch = 0; ch < chunk; ++ch) {
            float a = sA[ch * 1024 + chan];
            pR = a * pR + sR[ch * 1024 + chan];
            pI = a * pI + sI[ch * 1024 + chan];
        }
    }
    // sub-chunk summaries from scan_sum (replaces recompute pass)
    __shared__ float lA[256], lR[256], lI[256], pTR[256], pTI[256];
    {
        const int chan = b * K_ + kg * 16 + c;
        const int sidx = (chunk * 16 + t) * 1024 + chan;
        lA[c * 16 + t] = subA[sidx];
        lR[c * 16 + t] = subR[sidx];
        lI[c * 16 + t] = subI[sidx];
    }
    __syncthreads();
    if (tid < 16) {
        float r = pR, im = pI;
        for (int tt = 0; tt < 16; ++tt) {
            pTR[tid * 16 + tt] = r;
            pTI[tid * 16 + tt] = im;
            float at = lA[tid * 16 + tt];
            r  = at * r  + lR[tid * 16 + tt];
            im = at * im + lI[tid * 16 + tt];
        }
    }
    __syncthreads();
    // seeded walk + postprocess
    float r = pTR[c * 16 + t], im = pTI[c * 16 + t];
    unsigned short* orow = rho + (size_t)(b * N_ + n0) * DK2_ + k;
#pragma unroll
    for (int j = 0; j < 16; ++j) {
        Step s = compute_step<true>(base + (size_t)j * P_, __logf((float)(n0 + j + 1)));
        r  = s.alpha * r  + s.dr;
        im = s.alpha * im + s.di;
        float readout = r * s.cs + im * s.sn;
        float r2 = r  - s.beta * readout * s.cs;
        float i3 = im - s.beta * readout * s.sn;
        float mod = __fsqrt_rn(r2 * r2 + i3 * i3 + 1e-8f);
        float scl = fmaxf(mod, 1.0f);
        float inv = 1.0f / scl;
        float rr = r2 * inv, ri = i3 * inv;
        float rho_re = rr * s.cs + ri * s.sn;
        float rho_im = -rr * s.sn + ri * s.cs;
        orow[(size_t)j * DK2_]      = f2bf(s.g * rho_re);
        orow[(size_t)j * DK2_ + K_] = f2bf(s.g * rho_im);
    }
}

extern "C" void kernel_launch(void* const* d_in, const int* in_sizes, int n_in,
                              void* d_out, int out_size, void* d_ws, size_t ws_size,
                              hipStream_t stream) {
    const float* x  = (const float*)d_in[0];
    const float* Wp = (const float*)d_in[1];
    const float* bp = (const float*)d_in[2];
    const float* Wr = (const float*)d_in[3];
    const float* rs = (const float*)d_in[4];
    float* out = (float*)d_out;
    char* ws = (char*)d_ws;

    // workspace layout (bytes)
    _Float16* raw = (_Float16*)ws;                               // 16384*1536*2 = 50,331,648
    unsigned short* xb  = (unsigned short*)(ws + 100663296);     // 33,554,432
    unsigned short* wpb = (unsigned short*)(ws + 134217728);     // 3,145,728 (dead after GEMM1)
    unsigned short* wrb = (unsigned short*)(ws + 137363456);     // 1,048,576
    float* sA = (float*)(ws + 138412032);                        // 65,536
    float* sR = (float*)(ws + 138477568);                        // 65,536
    float* sI = (float*)(ws + 138543104);                        // 65,536
    unsigned short* rho = xb;            // alias: x_bf16 dead after GEMM1
    float* subA = (float*)(ws + 134217728);                      // alias wpb: 1 MB
    float* subR = (float*)(ws + 135266304);                      // 1 MB
    float* subI = (float*)(ws + 136314880);                      // 1 MB (ends at wrb)

    cvt_kernel<<<16384, 256, 0, stream>>>(x, xb, M_ * D_ / 4);
    cvt_kernel<<<1536, 256, 0, stream>>>(Wp, wpb, P_ * D_ / 4);
    cvt_kernel<<<512, 256, 0, stream>>>(Wr, wrb, D_ * DK2_ / 4);

    gemm_bt<256, 192, true, false, _Float16><<<dim3(M_ / 256, P_ / 192), 512, 0, stream>>>(
        xb, wpb, bp, nullptr, raw, M_, P_, D_);

    scan_sum_kernel<<<dim3(16, 16, 4), 256, 0, stream>>>(raw, sA, sR, sI, subA, subR, subI);
    scan_apply_kernel<<<dim3(16, 16, 4), 256, 0, stream>>>(raw, sA, sR, sI, subA, subR, subI, rho);

    gemm_bt<128, 128, false, true, float><<<dim3(M_ / 128, D_ / 128), 512, 0, stream>>>(
        rho, wrb, nullptr, rs, out, M_, D_, DK2_);
}

// Round 13
// 285.259 us; speedup vs baseline: 1.1621x; 1.1621x over previous
//
#include <hip/hip_runtime.h>
#include <hip/hip_bf16.h>
#include <cstdint>
#include <cstddef>

#define B_ 4
#define N_ 4096
#define D_ 1024
#define K_ 256
#define M_ (B_ * N_)          // 16384 rows
#define P_ (6 * K_)           // 1536 proj cols
#define DK2_ (2 * K_)         // 512 rho cols

static __device__ __forceinline__ float sigm(float x) {
    return 1.0f / (1.0f + __expf(-x));
}
static __device__ __forceinline__ float softplusf_(float x) {
    return fmaxf(x, 0.0f) + __logf(1.0f + __expf(-fabsf(x)));
}
static __device__ __forceinline__ unsigned short f2bf(float f) {
    uint32_t u = __float_as_uint(f);
    uint32_t r = (u + 0x7FFFu + ((u >> 16) & 1u)) >> 16;
    return (unsigned short)r;
}
static __device__ __forceinline__ uint32_t pk2bf(float lo, float hi) {
    return (uint32_t)f2bf(lo) | ((uint32_t)f2bf(hi) << 16);
}

#define GATE_BIAS 0.6190392084062235f
#define AMP_MAX 3.0f

typedef __attribute__((ext_vector_type(8))) __bf16 bf16x8;
typedef __attribute__((ext_vector_type(4))) float f32x4;

// async global->LDS, 16B per lane; lds dest must be wave-uniform base (HW adds lane*16)
static __device__ __forceinline__ void gload_lds16(const unsigned short* g, unsigned short* l) {
    __builtin_amdgcn_global_load_lds(
        (const __attribute__((address_space(1))) void*)g,
        (__attribute__((address_space(3))) void*)l, 16, 0, 0);
}

// ---------------- fp32 -> bf16 convert (weights only now) ----------------
__global__ __launch_bounds__(256) void cvt_kernel(const float* __restrict__ src,
                                                  unsigned short* __restrict__ dst, int n4) {
    int i = blockIdx.x * 256 + threadIdx.x;
    if (i < n4) {
        float4 v = reinterpret_cast<const float4*>(src)[i];
        ushort4 o;
        o.x = f2bf(v.x); o.y = f2bf(v.y); o.z = f2bf(v.z); o.w = f2bf(v.w);
        reinterpret_cast<ushort4*>(dst)[i] = o;
    }
}

// ---------------- bf16 GEMM, C[M][N] = A[M][Kd] * B[N][Kd]^T ----------------
// r8-exact structure (proven 62.5 us GEMM1): 256 x BN tile, BK=64, 8 waves
// (2M x 4N), wave tile 128 x BN/4, 2 static dbufs, one barrier per K-tile.
// CVTA=true (GEMM1): A is fp32 x, reg-staged with on-the-fly bf16 convert
// (T14 split): issue 8 float4 loads early, MFMA cluster covers the HBM
// latency, convert+ds_write_b128 after MFMAs, before lgkmcnt(0)+barrier.
// f2bf here == cvt_kernel's f2bf -> bitwise-identical A fragments.
// WAR safety unchanged: the written dbuf's last reads drained one barrier
// earlier; writes drained by this tile's lgkmcnt(0) before its barrier.
// CVTA=false (GEMM2): A bf16 via gload_lds16 (r8-exact).

// swizzled fragment read: row r, k-col kc (element units) from [rows]x64 tile
#define FRAG(BUF, r, kc) \
    (*reinterpret_cast<const bf16x8*>(&(BUF)[(size_t)(r) * 64 + (((((kc) >> 3) ^ ((r) & 7)) << 3))]))

template <int BN, bool CVTA, bool ADD_BIAS, bool SCALE, typename OutT>
__global__ __launch_bounds__(512, 2) void gemm_bt(const unsigned short* __restrict__ A,
                                                  const float* __restrict__ Af,
                                                  const unsigned short* __restrict__ Bm,
                                                  const float* __restrict__ bias,
                                                  const float* __restrict__ scale_p,
                                                  OutT* __restrict__ C, int M, int N, int Kd) {
    constexpr int NB = BN / 64;        // B-frags per wave
    constexpr int WCOL = BN / 4;       // wave column extent
    __shared__ unsigned short As0[256 * 64];
    __shared__ unsigned short Bs0[BN * 64];
    __shared__ unsigned short As1[256 * 64];
    __shared__ unsigned short Bs1[BN * 64];

    const int tid = threadIdx.x;
    const int w = tid >> 6, l = tid & 63;
    const int m0 = blockIdx.x * 256;
    const int n0 = blockIdx.y * BN;
    const int wm = w >> 2, wn = w & 3;         // 2 x 4 wave grid
    const int lr = l & 15, lk = (l >> 4) * 8;
    const int nt = Kd >> 6;                    // 16 (GEMM1) / 8 (GEMM2), even

    // staging geometry: group G covers rows G*64+srow, 8 slots of 8 elems
    const int srow = tid >> 3;                 // 0..63
    const int sslot = tid & 7;
    const int wbase = tid & ~63;
    const int acol = (sslot ^ (srow & 7)) << 3;   // swizzled elem col in row

    f32x4 acc[8][NB];
#pragma unroll
    for (int mi = 0; mi < 8; ++mi)
#pragma unroll
        for (int ni = 0; ni < NB; ++ni) acc[mi][ni] = (f32x4){0.f, 0.f, 0.f, 0.f};

#define A_GLOAD(PA, K0)                                                               \
    {                                                                                 \
        _Pragma("unroll") for (int g = 0; g < 4; ++g) {                               \
            int row = g * 64 + srow;                                                  \
            gload_lds16(A + (size_t)(m0 + row) * Kd + (K0) + acol,                    \
                        (PA) + ((g * 512 + wbase)) * 8);                              \
        }                                                                             \
    }
#define A_ISSUE(K0)                                                                   \
    {                                                                                 \
        _Pragma("unroll") for (int g = 0; g < 4; ++g) {                               \
            const float4* p = reinterpret_cast<const float4*>(                        \
                Af + (size_t)(m0 + g * 64 + srow) * Kd + (K0) + acol);                \
            av[g][0] = p[0];                                                          \
            av[g][1] = p[1];                                                          \
        }                                                                             \
    }
#define A_WRITE(PA)                                                                   \
    {                                                                                 \
        _Pragma("unroll") for (int g = 0; g < 4; ++g) {                               \
            int4 wv;                                                                  \
            wv.x = (int)pk2bf(av[g][0].x, av[g][0].y);                                \
            wv.y = (int)pk2bf(av[g][0].z, av[g][0].w);                                \
            wv.z = (int)pk2bf(av[g][1].x, av[g][1].y);                                \
            wv.w = (int)pk2bf(av[g][1].z, av[g][1].w);                                \
            *reinterpret_cast<int4*>(&(PA)[(size_t)g * 4096 + tid * 8]) = wv;         \
        }                                                                             \
    }
#define B_GLOAD(PB, K0)                                                               \
    {                                                                                 \
        _Pragma("unroll") for (int g = 0; g < NB; ++g) {                              \
            int row = g * 64 + srow;                                                  \
            gload_lds16(Bm + (size_t)(n0 + row) * Kd + (K0) + acol,                   \
                        (PB) + ((g * 512 + wbase)) * 8);                              \
        }                                                                             \
    }

#define TILE_STEP(T, CA, CB, PA, PB)                                                  \
    {                                                                                 \
        const int knext = ((T) + 1) * 64;                                             \
        const bool ds = ((T) + 1 < nt);                                               \
        float4 av[4][2];                                                              \
        if (ds) {                                                                     \
            if constexpr (CVTA) { A_ISSUE(knext); } else { A_GLOAD(PA, knext); }      \
            B_GLOAD(PB, knext);                                                       \
        }                                                                             \
        _Pragma("unroll") for (int kkI = 0; kkI < 2; ++kkI) {                         \
            const int kk = kkI * 32;                                                  \
            bf16x8 af[8], bfr[NB];                                                    \
            _Pragma("unroll") for (int f = 0; f < 8; ++f) {                           \
                int ar = wm * 128 + f * 16 + lr;                                      \
                af[f] = FRAG(CA, ar, kk + lk);                                        \
            }                                                                         \
            _Pragma("unroll") for (int f = 0; f < NB; ++f) {                          \
                int br = wn * WCOL + f * 16 + lr;                                     \
                bfr[f] = FRAG(CB, br, kk + lk);                                       \
            }                                                                         \
            __builtin_amdgcn_s_setprio(1);                                            \
            _Pragma("unroll") for (int mi = 0; mi < 8; ++mi)                          \
                _Pragma("unroll") for (int ni = 0; ni < NB; ++ni)                     \
                    acc[mi][ni] = __builtin_amdgcn_mfma_f32_16x16x32_bf16(            \
                        af[mi], bfr[ni], acc[mi][ni], 0, 0, 0);                       \
            __builtin_amdgcn_s_setprio(0);                                            \
        }                                                                             \
        if (ds) {                                                                     \
            if constexpr (CVTA) { A_WRITE(PA); }                                      \
        }                                                                             \
        asm volatile("s_waitcnt vmcnt(0) lgkmcnt(0)" ::: "memory");                   \
        __builtin_amdgcn_s_barrier();                                                 \
    }

    // prologue: stage tile 0 into dbuf0, drain, barrier
    {
        float4 av[4][2];
        if constexpr (CVTA) {
            A_ISSUE(0);
            A_WRITE(As0);
        } else {
            A_GLOAD(As0, 0);
        }
        B_GLOAD(Bs0, 0);
        asm volatile("s_waitcnt vmcnt(0) lgkmcnt(0)" ::: "memory");
        __builtin_amdgcn_s_barrier();
    }

    for (int t = 0; t < nt; t += 2) {
        TILE_STEP(t, As0, Bs0, As1, Bs1);
        TILE_STEP(t + 1, As1, Bs1, As0, Bs0);
    }

    float sc = SCALE ? *scale_p : 1.0f;
#pragma unroll
    for (int mi = 0; mi < 8; ++mi) {
        int row = m0 + wm * 128 + mi * 16 + (l >> 4) * 4;
#pragma unroll
        for (int ni = 0; ni < NB; ++ni) {
            int col = n0 + wn * WCOL + ni * 16 + lr;
            float bv = ADD_BIAS ? bias[col] : 0.0f;
#pragma unroll
            for (int j = 0; j < 4; ++j) {
                float v = acc[mi][ni][j] + bv;
                if (SCALE) v *= sc;
                C[(size_t)(row + j) * N + col] = (OutT)v;
            }
        }
    }
#undef A_GLOAD
#undef A_ISSUE
#undef A_WRITE
#undef B_GLOAD
#undef TILE_STEP
}

// ---------------- per-step oscillator math (fp16 raw) ----------------
struct Step {
    float alpha, dr, di, cs, sn, g, beta;
};
template <bool FULL>
static __device__ __forceinline__ Step compute_step(const _Float16* __restrict__ p, float pos) {
    Step s;
    float a_raw = (float)p[0];
    float o_raw = (float)p[K_];
    float phi   = (float)p[2 * K_];
    float al    = (float)p[3 * K_];
    float A     = AMP_MAX * sigm(a_raw);
    float omega = softplusf_(o_raw);
    float alpha = sigm(al + GATE_BIAS);
    float angle = omega * pos + phi;
    float sn, cs;
    __sincosf(angle, &sn, &cs);
    float oma = 1.0f - alpha;
    s.alpha = alpha;
    s.dr = oma * A * cs;
    s.di = oma * A * sn;
    s.cs = cs;
    s.sn = sn;
    if (FULL) {
        s.g    = sigm((float)p[4 * K_]);
        s.beta = sigm((float)p[5 * K_]);
    }
    return s;
}

// ---------------- scan stage 1: chunk + sub-chunk summaries ----------------
// grid: (chunk=16, kgroup=16, b=4); block: 256 = 16 channels x 16 sub-chunks of 16 steps
__global__ __launch_bounds__(256) void scan_sum_kernel(const _Float16* __restrict__ raw,
                                                       float* __restrict__ sA,
                                                       float* __restrict__ sR,
                                                       float* __restrict__ sI,
                                                       float* __restrict__ subA,
                                                       float* __restrict__ subR,
                                                       float* __restrict__ subI) {
    const int tid = threadIdx.x;
    const int c = tid & 15, t = tid >> 4;
    const int chunk = blockIdx.x, kg = blockIdx.y, b = blockIdx.z;
    const int k = kg * 16 + c;
    const int n0 = chunk * 256 + t * 16;
    const _Float16* base = raw + (size_t)(b * N_ + n0) * P_ + k;

    float aP = 1.0f, rR = 0.0f, rI = 0.0f;
#pragma unroll
    for (int j = 0; j < 16; ++j) {
        Step s = compute_step<false>(base + (size_t)j * P_, __logf((float)(n0 + j + 1)));
        aP *= s.alpha;
        rR = s.alpha * rR + s.dr;
        rI = s.alpha * rI + s.di;
    }
    // sub-chunk summary -> global (consumed by scan_apply instead of recompute)
    const int chan = b * K_ + kg * 16 + c;
    const int sidx = (chunk * 16 + t) * 1024 + chan;
    subA[sidx] = aP;
    subR[sidx] = rR;
    subI[sidx] = rI;

    __shared__ float lA[256], lR[256], lI[256];
    lA[c * 16 + t] = aP;
    lR[c * 16 + t] = rR;
    lI[c * 16 + t] = rI;
    __syncthreads();
    if (tid < 16) {
        float a = 1.0f, r = 0.0f, im = 0.0f;
        for (int tt = 0; tt < 16; ++tt) {
            float at = lA[tid * 16 + tt];
            r  = at * r  + lR[tid * 16 + tt];
            im = at * im + lI[tid * 16 + tt];
            a *= at;
        }
        int chanw = b * K_ + kg * 16 + tid;
        sA[chunk * 1024 + chanw] = a;
        sR[chunk * 1024 + chanw] = r;
        sI[chunk * 1024 + chanw] = im;
    }
}

// ---------------- scan stage 2: apply + postprocess -> rho (bf16) ----------------
__global__ __launch_bounds__(256) void scan_apply_kernel(const _Float16* __restrict__ raw,
                                                         const float* __restrict__ sA,
                                                         const float* __restrict__ sR,
                                                         const float* __restrict__ sI,
                                                         const float* __restrict__ subA,
                                                         const float* __restrict__ subR,
                                                         const float* __restrict__ subI,
                                                         unsigned short* __restrict__ rho) {
    const int tid = threadIdx.x;
    const int c = tid & 15, t = tid >> 4;
    const int chunk = blockIdx.x, kg = blockIdx.y, b = blockIdx.z;
    const int k = kg * 16 + c;
    const int n0 = chunk * 256 + t * 16;
    const _Float16* base = raw + (size_t)(b * N_ + n0) * P_ + k;

    // chunk-prefix (exclusive) for channel handled by lanes tid<16
    float pR = 0.0f, pI = 0.0f;
    if (tid < 16) {
        int chan = b * K_ + kg * 16 + tid;
        for (int ch = 0; ch < chunk; ++ch) {
            float a = sA[ch * 1024 + chan];
            pR = a * pR + sR[ch * 1024 + chan];
            pI = a * pI + sI[ch * 1024 + chan];
        }
    }
    // sub-chunk summaries from scan_sum (replaces recompute pass)
    __shared__ float lA[256], lR[256], lI[256], pTR[256], pTI[256];
    {
        const int chan = b * K_ + kg * 16 + c;
        const int sidx = (chunk * 16 + t) * 1024 + chan;
        lA[c * 16 + t] = subA[sidx];
        lR[c * 16 + t] = subR[sidx];
        lI[c * 16 + t] = subI[sidx];
    }
    __syncthreads();
    if (tid < 16) {
        float r = pR, im = pI;
        for (int tt = 0; tt < 16; ++tt) {
            pTR[tid * 16 + tt] = r;
            pTI[tid * 16 + tt] = im;
            float at = lA[tid * 16 + tt];
            r  = at * r  + lR[tid * 16 + tt];
            im = at * im + lI[tid * 16 + tt];
        }
    }
    __syncthreads();
    // seeded walk + postprocess
    float r = pTR[c * 16 + t], im = pTI[c * 16 + t];
    unsigned short* orow = rho + (size_t)(b * N_ + n0) * DK2_ + k;
#pragma unroll
    for (int j = 0; j < 16; ++j) {
        Step s = compute_step<true>(base + (size_t)j * P_, __logf((float)(n0 + j + 1)));
        r  = s.alpha * r  + s.dr;
        im = s.alpha * im + s.di;
        float readout = r * s.cs + im * s.sn;
        float r2 = r  - s.beta * readout * s.cs;
        float i3 = im - s.beta * readout * s.sn;
        float mod = __fsqrt_rn(r2 * r2 + i3 * i3 + 1e-8f);
        float scl = fmaxf(mod, 1.0f);
        float inv = 1.0f / scl;
        float rr = r2 * inv, ri = i3 * inv;
        float rho_re = rr * s.cs + ri * s.sn;
        float rho_im = -rr * s.sn + ri * s.cs;
        orow[(size_t)j * DK2_]      = f2bf(s.g * rho_re);
        orow[(size_t)j * DK2_ + K_] = f2bf(s.g * rho_im);
    }
}

extern "C" void kernel_launch(void* const* d_in, const int* in_sizes, int n_in,
                              void* d_out, int out_size, void* d_ws, size_t ws_size,
                              hipStream_t stream) {
    const float* x  = (const float*)d_in[0];
    const float* Wp = (const float*)d_in[1];
    const float* bp = (const float*)d_in[2];
    const float* Wr = (const float*)d_in[3];
    const float* rs = (const float*)d_in[4];
    float* out = (float*)d_out;
    char* ws = (char*)d_ws;

    // workspace layout (bytes)
    _Float16* raw = (_Float16*)ws;                               // 16384*1536*2 = 50,331,648
    unsigned short* rho = (unsigned short*)(ws + 100663296);     // 16,777,216
    unsigned short* wpb = (unsigned short*)(ws + 134217728 - 4194304); // 3,145,728 (wait region)
    unsigned short* wrb = (unsigned short*)(ws + 137363456);     // 1,048,576
    float* sA = (float*)(ws + 138412032);                        // 65,536
    float* sR = (float*)(ws + 138477568);                        // 65,536
    float* sI = (float*)(ws + 138543104);                        // 65,536
    float* subA = (float*)(ws + 119537664);                      // 1 MB (after rho region)
    float* subR = (float*)(ws + 120586240);                      // 1 MB
    float* subI = (float*)(ws + 121634816);                      // 1 MB

    cvt_kernel<<<1536, 256, 0, stream>>>(Wp, wpb, P_ * D_ / 4);
    cvt_kernel<<<512, 256, 0, stream>>>(Wr, wrb, D_ * DK2_ / 4);

    // GEMM1: A = x (fp32, reg-staged + converted in-kernel), B = Wp bf16
    gemm_bt<192, true, true, false, _Float16><<<dim3(M_ / 256, P_ / 192), 512, 0, stream>>>(
        nullptr, x, wpb, bp, nullptr, raw, M_, P_, D_);

    scan_sum_kernel<<<dim3(16, 16, 4), 256, 0, stream>>>(raw, sA, sR, sI, subA, subR, subI);
    scan_apply_kernel<<<dim3(16, 16, 4), 256, 0, stream>>>(raw, sA, sR, sI, subA, subR, subI, rho);

    // GEMM2: A = rho bf16 (gload_lds path), B = Wr bf16
    gemm_bt<256, false, false, true, float><<<dim3(M_ / 256, D_ / 256), 512, 0, stream>>>(
        rho, nullptr, wrb, nullptr, rs, out, M_, D_, DK2_);
}

// Round 14
// 155.100 us; speedup vs baseline: 2.1374x; 1.8392x over previous
//
#include <hip/hip_runtime.h>
#include <hip/hip_bf16.h>
#include <cstdint>
#include <cstddef>

#define B_ 4
#define N_ 4096
#define D_ 1024
#define K_ 256
#define M_ (B_ * N_)          // 16384 rows
#define P_ (6 * K_)           // 1536 proj cols
#define DK2_ (2 * K_)         // 512 rho cols

static __device__ __forceinline__ float sigm(float x) {
    return 1.0f / (1.0f + __expf(-x));
}
static __device__ __forceinline__ float softplusf_(float x) {
    return fmaxf(x, 0.0f) + __logf(1.0f + __expf(-fabsf(x)));
}
static __device__ __forceinline__ unsigned short f2bf(float f) {
    uint32_t u = __float_as_uint(f);
    uint32_t r = (u + 0x7FFFu + ((u >> 16) & 1u)) >> 16;
    return (unsigned short)r;
}
static __device__ __forceinline__ uint32_t pk2bf(float lo, float hi) {
    return (uint32_t)f2bf(lo) | ((uint32_t)f2bf(hi) << 16);
}

#define GATE_BIAS 0.6190392084062235f
#define AMP_MAX 3.0f

typedef __attribute__((ext_vector_type(8))) __bf16 bf16x8;
typedef __attribute__((ext_vector_type(4))) float f32x4;

// async global->LDS, 16B per lane; lds dest must be wave-uniform base (HW adds lane*16)
static __device__ __forceinline__ void gload_lds16(const unsigned short* g, unsigned short* l) {
    __builtin_amdgcn_global_load_lds(
        (const __attribute__((address_space(1))) void*)g,
        (__attribute__((address_space(3))) void*)l, 16, 0, 0);
}

// ---------------- fp32 -> bf16 convert: both weight matrices, one launch ----------------
__global__ __launch_bounds__(256) void cvt2_kernel(const float* __restrict__ s0,
                                                   unsigned short* __restrict__ d0, int n0_,
                                                   const float* __restrict__ s1,
                                                   unsigned short* __restrict__ d1) {
    int i = blockIdx.x * 256 + threadIdx.x;
    const float* s = (i < n0_) ? s0 : s1;
    unsigned short* d = (i < n0_) ? d0 : d1;
    int j = (i < n0_) ? i : (i - n0_);
    float4 v = reinterpret_cast<const float4*>(s)[j];
    ushort4 o;
    o.x = f2bf(v.x); o.y = f2bf(v.y); o.z = f2bf(v.z); o.w = f2bf(v.w);
    reinterpret_cast<ushort4*>(d)[j] = o;
}

// ---------------- bf16 GEMM, C[M][N] = A[M][Kd] * B[N][Kd]^T ----------------
// r8-exact core (proven 62.5 us GEMM1): 256 x BN tile, BK=64, 8 waves
// (2M x 4N), wave tile 128 x BN/4, 2 static dbufs, one barrier per K-tile.
// CVTA=true (GEMM1): A is fp32 x with fused bf16 convert, BATCH-SPLIT to
// avoid the r13 register spill (peak live = 2 rows = 16 VGPRs, not 32):
//   issue batch0 (rows g=0,1) + B_GLOAD -> kkI=0 MFMAs (latency cover)
//   write batch0 to LDS; issue batch1 (g=2,3) -> kkI=1 MFMAs (cover)
//   write batch1; lgkmcnt(0)+vmcnt(0); barrier.
// x is 64 MB -> L3-resident across the 6 column-tile re-reads, so batch1's
// shorter cover (one MFMA cluster) suffices for the L2/L3-hit latency.
// f2bf == cvt kernel's f2bf -> bitwise-identical A fragments (absmax same).
// WAR safety unchanged: writes target the other dbuf, drained by this
// tile's lgkmcnt(0) before its barrier.

// swizzled fragment read: row r, k-col kc (element units) from [rows]x64 tile
#define FRAG(BUF, r, kc) \
    (*reinterpret_cast<const bf16x8*>(&(BUF)[(size_t)(r) * 64 + (((((kc) >> 3) ^ ((r) & 7)) << 3))]))

template <int BN, bool CVTA, bool ADD_BIAS, bool SCALE, typename OutT>
__global__ __launch_bounds__(512, 2) void gemm_bt(const unsigned short* __restrict__ A,
                                                  const float* __restrict__ Af,
                                                  const unsigned short* __restrict__ Bm,
                                                  const float* __restrict__ bias,
                                                  const float* __restrict__ scale_p,
                                                  OutT* __restrict__ C, int M, int N, int Kd) {
    constexpr int NB = BN / 64;        // B-frags per wave
    constexpr int WCOL = BN / 4;       // wave column extent
    __shared__ unsigned short As0[256 * 64];
    __shared__ unsigned short Bs0[BN * 64];
    __shared__ unsigned short As1[256 * 64];
    __shared__ unsigned short Bs1[BN * 64];

    const int tid = threadIdx.x;
    const int w = tid >> 6, l = tid & 63;
    const int m0 = blockIdx.x * 256;
    const int n0 = blockIdx.y * BN;
    const int wm = w >> 2, wn = w & 3;         // 2 x 4 wave grid
    const int lr = l & 15, lk = (l >> 4) * 8;
    const int nt = Kd >> 6;                    // 16 (GEMM1) / 8 (GEMM2), even

    // staging geometry: group G covers rows G*64+srow, 8 slots of 8 elems
    const int srow = tid >> 3;                 // 0..63
    const int sslot = tid & 7;
    const int wbase = tid & ~63;
    const int acol = (sslot ^ (srow & 7)) << 3;   // swizzled elem col in row

    f32x4 acc[8][NB];
#pragma unroll
    for (int mi = 0; mi < 8; ++mi)
#pragma unroll
        for (int ni = 0; ni < NB; ++ni) acc[mi][ni] = (f32x4){0.f, 0.f, 0.f, 0.f};

#define A_GLOAD(PA, K0)                                                               \
    {                                                                                 \
        _Pragma("unroll") for (int g = 0; g < 4; ++g) {                               \
            int row = g * 64 + srow;                                                  \
            gload_lds16(A + (size_t)(m0 + row) * Kd + (K0) + acol,                    \
                        (PA) + ((g * 512 + wbase)) * 8);                              \
        }                                                                             \
    }
// issue 2 rows of fp32 A (batch H: rows H*2, H*2+1) into AV[2][2]
#define A_ISSUE2(AV, K0, H)                                                           \
    {                                                                                 \
        _Pragma("unroll") for (int g = 0; g < 2; ++g) {                               \
            const float4* p = reinterpret_cast<const float4*>(                        \
                Af + (size_t)(m0 + ((H) * 2 + g) * 64 + srow) * Kd + (K0) + acol);    \
            AV[g][0] = p[0];                                                          \
            AV[g][1] = p[1];                                                          \
        }                                                                             \
    }
#define A_WRITE2(AV, PA, H)                                                           \
    {                                                                                 \
        _Pragma("unroll") for (int g = 0; g < 2; ++g) {                               \
            int4 wv;                                                                  \
            wv.x = (int)pk2bf(AV[g][0].x, AV[g][0].y);                                \
            wv.y = (int)pk2bf(AV[g][0].z, AV[g][0].w);                                \
            wv.z = (int)pk2bf(AV[g][1].x, AV[g][1].y);                                \
            wv.w = (int)pk2bf(AV[g][1].z, AV[g][1].w);                                \
            *reinterpret_cast<int4*>(&(PA)[(size_t)((H) * 2 + g) * 4096 + tid * 8]) = wv; \
        }                                                                             \
    }
#define B_GLOAD(PB, K0)                                                               \
    {                                                                                 \
        _Pragma("unroll") for (int g = 0; g < NB; ++g) {                              \
            int row = g * 64 + srow;                                                  \
            gload_lds16(Bm + (size_t)(n0 + row) * Kd + (K0) + acol,                   \
                        (PB) + ((g * 512 + wbase)) * 8);                              \
        }                                                                             \
    }

#define KK_BLOCK(CA, CB, KK)                                                          \
    {                                                                                 \
        bf16x8 af[8], bfr[NB];                                                        \
        _Pragma("unroll") for (int f = 0; f < 8; ++f) {                               \
            int ar = wm * 128 + f * 16 + lr;                                          \
            af[f] = FRAG(CA, ar, (KK) + lk);                                          \
        }                                                                             \
        _Pragma("unroll") for (int f = 0; f < NB; ++f) {                              \
            int br = wn * WCOL + f * 16 + lr;                                         \
            bfr[f] = FRAG(CB, br, (KK) + lk);                                         \
        }                                                                             \
        __builtin_amdgcn_s_setprio(1);                                                \
        _Pragma("unroll") for (int mi = 0; mi < 8; ++mi)                              \
            _Pragma("unroll") for (int ni = 0; ni < NB; ++ni)                         \
                acc[mi][ni] = __builtin_amdgcn_mfma_f32_16x16x32_bf16(                \
                    af[mi], bfr[ni], acc[mi][ni], 0, 0, 0);                           \
        __builtin_amdgcn_s_setprio(0);                                                \
    }

#define TILE_STEP(T, CA, CB, PA, PB)                                                  \
    {                                                                                 \
        const int knext = ((T) + 1) * 64;                                             \
        const bool ds = ((T) + 1 < nt);                                               \
        float4 av[2][2];                                                              \
        if (ds) {                                                                     \
            if constexpr (CVTA) { A_ISSUE2(av, knext, 0); } else { A_GLOAD(PA, knext); } \
            B_GLOAD(PB, knext);                                                       \
        }                                                                             \
        KK_BLOCK(CA, CB, 0);                                                          \
        if constexpr (CVTA) {                                                         \
            if (ds) { A_WRITE2(av, PA, 0); A_ISSUE2(av, knext, 1); }                  \
        }                                                                             \
        KK_BLOCK(CA, CB, 32);                                                         \
        if constexpr (CVTA) {                                                         \
            if (ds) { A_WRITE2(av, PA, 1); }                                          \
        }                                                                             \
        asm volatile("s_waitcnt vmcnt(0) lgkmcnt(0)" ::: "memory");                   \
        __builtin_amdgcn_s_barrier();                                                 \
    }

    // prologue: stage tile 0 into dbuf0, drain, barrier
    {
        float4 av[2][2];
        if constexpr (CVTA) {
            A_ISSUE2(av, 0, 0);
            A_WRITE2(av, As0, 0);
            A_ISSUE2(av, 0, 1);
            A_WRITE2(av, As0, 1);
        } else {
            A_GLOAD(As0, 0);
        }
        B_GLOAD(Bs0, 0);
        asm volatile("s_waitcnt vmcnt(0) lgkmcnt(0)" ::: "memory");
        __builtin_amdgcn_s_barrier();
    }

    for (int t = 0; t < nt; t += 2) {
        TILE_STEP(t, As0, Bs0, As1, Bs1);
        TILE_STEP(t + 1, As1, Bs1, As0, Bs0);
    }

    float sc = SCALE ? *scale_p : 1.0f;
#pragma unroll
    for (int mi = 0; mi < 8; ++mi) {
        int row = m0 + wm * 128 + mi * 16 + (l >> 4) * 4;
#pragma unroll
        for (int ni = 0; ni < NB; ++ni) {
            int col = n0 + wn * WCOL + ni * 16 + lr;
            float bv = ADD_BIAS ? bias[col] : 0.0f;
#pragma unroll
            for (int j = 0; j < 4; ++j) {
                float v = acc[mi][ni][j] + bv;
                if (SCALE) v *= sc;
                C[(size_t)(row + j) * N + col] = (OutT)v;
            }
        }
    }
#undef A_GLOAD
#undef A_ISSUE2
#undef A_WRITE2
#undef B_GLOAD
#undef KK_BLOCK
#undef TILE_STEP
}

// ---------------- per-step oscillator math (fp16 raw) ----------------
struct Step {
    float alpha, dr, di, cs, sn, g, beta;
};
template <bool FULL>
static __device__ __forceinline__ Step compute_step(const _Float16* __restrict__ p, float pos) {
    Step s;
    float a_raw = (float)p[0];
    float o_raw = (float)p[K_];
    float phi   = (float)p[2 * K_];
    float al    = (float)p[3 * K_];
    float A     = AMP_MAX * sigm(a_raw);
    float omega = softplusf_(o_raw);
    float alpha = sigm(al + GATE_BIAS);
    float angle = omega * pos + phi;
    float sn, cs;
    __sincosf(angle, &sn, &cs);
    float oma = 1.0f - alpha;
    s.alpha = alpha;
    s.dr = oma * A * cs;
    s.di = oma * A * sn;
    s.cs = cs;
    s.sn = sn;
    if (FULL) {
        s.g    = sigm((float)p[4 * K_]);
        s.beta = sigm((float)p[5 * K_]);
    }
    return s;
}

// ---------------- scan stage 1: chunk + sub-chunk summaries ----------------
// grid: (chunk=16, kgroup=16, b=4); block: 256 = 16 channels x 16 sub-chunks of 16 steps
__global__ __launch_bounds__(256) void scan_sum_kernel(const _Float16* __restrict__ raw,
                                                       float* __restrict__ sA,
                                                       float* __restrict__ sR,
                                                       float* __restrict__ sI,
                                                       float* __restrict__ subA,
                                                       float* __restrict__ subR,
                                                       float* __restrict__ subI) {
    const int tid = threadIdx.x;
    const int c = tid & 15, t = tid >> 4;
    const int chunk = blockIdx.x, kg = blockIdx.y, b = blockIdx.z;
    const int k = kg * 16 + c;
    const int n0 = chunk * 256 + t * 16;
    const _Float16* base = raw + (size_t)(b * N_ + n0) * P_ + k;

    float aP = 1.0f, rR = 0.0f, rI = 0.0f;
#pragma unroll
    for (int j = 0; j < 16; ++j) {
        Step s = compute_step<false>(base + (size_t)j * P_, __logf((float)(n0 + j + 1)));
        aP *= s.alpha;
        rR = s.alpha * rR + s.dr;
        rI = s.alpha * rI + s.di;
    }
    // sub-chunk summary -> global (consumed by scan_apply instead of recompute)
    const int chan = b * K_ + kg * 16 + c;
    const int sidx = (chunk * 16 + t) * 1024 + chan;
    subA[sidx] = aP;
    subR[sidx] = rR;
    subI[sidx] = rI;

    __shared__ float lA[256], lR[256], lI[256];
    lA[c * 16 + t] = aP;
    lR[c * 16 + t] = rR;
    lI[c * 16 + t] = rI;
    __syncthreads();
    if (tid < 16) {
        float a = 1.0f, r = 0.0f, im = 0.0f;
        for (int tt = 0; tt < 16; ++tt) {
            float at = lA[tid * 16 + tt];
            r  = at * r  + lR[tid * 16 + tt];
            im = at * im + lI[tid * 16 + tt];
            a *= at;
        }
        int chanw = b * K_ + kg * 16 + tid;
        sA[chunk * 1024 + chanw] = a;
        sR[chunk * 1024 + chanw] = r;
        sI[chunk * 1024 + chanw] = im;
    }
}

// ---------------- scan stage 2: apply + postprocess -> rho (bf16) ----------------
__global__ __launch_bounds__(256) void scan_apply_kernel(const _Float16* __restrict__ raw,
                                                         const float* __restrict__ sA,
                                                         const float* __restrict__ sR,
                                                         const float* __restrict__ sI,
                                                         const float* __restrict__ subA,
                                                         const float* __restrict__ subR,
                                                         const float* __restrict__ subI,
                                                         unsigned short* __restrict__ rho) {
    const int tid = threadIdx.x;
    const int c = tid & 15, t = tid >> 4;
    const int chunk = blockIdx.x, kg = blockIdx.y, b = blockIdx.z;
    const int k = kg * 16 + c;
    const int n0 = chunk * 256 + t * 16;
    const _Float16* base = raw + (size_t)(b * N_ + n0) * P_ + k;

    // chunk-prefix (exclusive) for channel handled by lanes tid<16
    float pR = 0.0f, pI = 0.0f;
    if (tid < 16) {
        int chan = b * K_ + kg * 16 + tid;
        for (int ch = 0; ch < chunk; ++ch) {
            float a = sA[ch * 1024 + chan];
            pR = a * pR + sR[ch * 1024 + chan];
            pI = a * pI + sI[ch * 1024 + chan];
        }
    }
    // sub-chunk summaries from scan_sum (replaces recompute pass)
    __shared__ float lA[256], lR[256], lI[256], pTR[256], pTI[256];
    {
        const int chan = b * K_ + kg * 16 + c;
        const int sidx = (chunk * 16 + t) * 1024 + chan;
        lA[c * 16 + t] = subA[sidx];
        lR[c * 16 + t] = subR[sidx];
        lI[c * 16 + t] = subI[sidx];
    }
    __syncthreads();
    if (tid < 16) {
        float r = pR, im = pI;
        for (int tt = 0; tt < 16; ++tt) {
            pTR[tid * 16 + tt] = r;
            pTI[tid * 16 + tt] = im;
            float at = lA[tid * 16 + tt];
            r  = at * r  + lR[tid * 16 + tt];
            im = at * im + lI[tid * 16 + tt];
        }
    }
    __syncthreads();
    // seeded walk + postprocess
    float r = pTR[c * 16 + t], im = pTI[c * 16 + t];
    unsigned short* orow = rho + (size_t)(b * N_ + n0) * DK2_ + k;
#pragma unroll
    for (int j = 0; j < 16; ++j) {
        Step s = compute_step<true>(base + (size_t)j * P_, __logf((float)(n0 + j + 1)));
        r  = s.alpha * r  + s.dr;
        im = s.alpha * im + s.di;
        float readout = r * s.cs + im * s.sn;
        float r2 = r  - s.beta * readout * s.cs;
        float i3 = im - s.beta * readout * s.sn;
        float mod = __fsqrt_rn(r2 * r2 + i3 * i3 + 1e-8f);
        float scl = fmaxf(mod, 1.0f);
        float inv = 1.0f / scl;
        float rr = r2 * inv, ri = i3 * inv;
        float rho_re = rr * s.cs + ri * s.sn;
        float rho_im = -rr * s.sn + ri * s.cs;
        orow[(size_t)j * DK2_]      = f2bf(s.g * rho_re);
        orow[(size_t)j * DK2_ + K_] = f2bf(s.g * rho_im);
    }
}

extern "C" void kernel_launch(void* const* d_in, const int* in_sizes, int n_in,
                              void* d_out, int out_size, void* d_ws, size_t ws_size,
                              hipStream_t stream) {
    const float* x  = (const float*)d_in[0];
    const float* Wp = (const float*)d_in[1];
    const float* bp = (const float*)d_in[2];
    const float* Wr = (const float*)d_in[3];
    const float* rs = (const float*)d_in[4];
    float* out = (float*)d_out;
    char* ws = (char*)d_ws;

    // workspace layout (bytes)
    _Float16* raw = (_Float16*)ws;                               // 16384*1536*2 = 50,331,648
    unsigned short* rho = (unsigned short*)(ws + 100663296);     // 16,777,216
    unsigned short* wpb = (unsigned short*)(ws + 130023424);     // 3,145,728
    unsigned short* wrb = (unsigned short*)(ws + 137363456);     // 1,048,576
    float* sA = (float*)(ws + 138412032);                        // 65,536
    float* sR = (float*)(ws + 138477568);                        // 65,536
    float* sI = (float*)(ws + 138543104);                        // 65,536
    float* subA = (float*)(ws + 119537664);                      // 1 MB
    float* subR = (float*)(ws + 120586240);                      // 1 MB
    float* subI = (float*)(ws + 121634816);                      // 1 MB

    cvt2_kernel<<<2048, 256, 0, stream>>>(Wp, wpb, P_ * D_ / 4, Wr, wrb);

    // GEMM1: A = x (fp32, fused batch-split convert), B = Wp bf16
    gemm_bt<192, true, true, false, _Float16><<<dim3(M_ / 256, P_ / 192), 512, 0, stream>>>(
        nullptr, x, wpb, bp, nullptr, raw, M_, P_, D_);

    scan_sum_kernel<<<dim3(16, 16, 4), 256, 0, stream>>>(raw, sA, sR, sI, subA, subR, subI);
    scan_apply_kernel<<<dim3(16, 16, 4), 256, 0, stream>>>(raw, sA, sR, sI, subA, subR, subI, rho);

    // GEMM2: A = rho bf16 (gload_lds path), B = Wr bf16
    gemm_bt<256, false, false, true, float><<<dim3(M_ / 256, D_ / 256), 512, 0, stream>>>(
        rho, nullptr, wrb, nullptr, rs, out, M_, D_, DK2_);
}

// Round 15
// 139.166 us; speedup vs baseline: 2.3821x; 1.1145x over previous
//
#include <hip/hip_runtime.h>
#include <hip/hip_bf16.h>
#include <cstdint>
#include <cstddef>

#define B_ 4
#define N_ 4096
#define D_ 1024
#define K_ 256
#define M_ (B_ * N_)          // 16384 rows
#define P_ (6 * K_)           // 1536 proj cols
#define DK2_ (2 * K_)         // 512 rho cols

static __device__ __forceinline__ float sigm(float x) {
    return 1.0f / (1.0f + __expf(-x));
}
static __device__ __forceinline__ float softplusf_(float x) {
    return fmaxf(x, 0.0f) + __logf(1.0f + __expf(-fabsf(x)));
}
static __device__ __forceinline__ unsigned short f2bf(float f) {
    uint32_t u = __float_as_uint(f);
    uint32_t r = (u + 0x7FFFu + ((u >> 16) & 1u)) >> 16;
    return (unsigned short)r;
}

#define GATE_BIAS 0.6190392084062235f
#define AMP_MAX 3.0f

typedef __attribute__((ext_vector_type(8))) __bf16 bf16x8;
typedef __attribute__((ext_vector_type(4))) float f32x4;

// async global->LDS, 16B per lane; lds dest must be wave-uniform base (HW adds lane*16)
static __device__ __forceinline__ void gload_lds16(const unsigned short* g, unsigned short* l) {
    __builtin_amdgcn_global_load_lds(
        (const __attribute__((address_space(1))) void*)g,
        (__attribute__((address_space(3))) void*)l, 16, 0, 0);
}

// ---------------- fp32 -> bf16 convert: x, Wp, Wr in ONE launch ----------------
__global__ __launch_bounds__(256) void cvt3_kernel(const float* __restrict__ s0,
                                                   unsigned short* __restrict__ d0, int n0_,
                                                   const float* __restrict__ s1,
                                                   unsigned short* __restrict__ d1, int n1_,
                                                   const float* __restrict__ s2,
                                                   unsigned short* __restrict__ d2) {
    int i = blockIdx.x * 256 + threadIdx.x;
    const float* s;
    unsigned short* d;
    int j;
    if (i < n0_)            { s = s0; d = d0; j = i; }
    else if (i < n0_ + n1_) { s = s1; d = d1; j = i - n0_; }
    else                    { s = s2; d = d2; j = i - n0_ - n1_; }
    float4 v = reinterpret_cast<const float4*>(s)[j];
    ushort4 o;
    o.x = f2bf(v.x); o.y = f2bf(v.y); o.z = f2bf(v.z); o.w = f2bf(v.w);
    reinterpret_cast<ushort4*>(d)[j] = o;
}

// ---------------- bf16 GEMM, C[M][N] = A[M][Kd] * B[N][Kd]^T ----------------
// r8-exact (proven best: GEMM1 62.5 us): 256 x BN tile, BK=64, 8 waves
// (2M x 4N), wave tile 128 x BN/4, 2 static dbufs, one barrier per K-tile.
// Per tile: stage next tile (gload_lds, pre-swizzled source), read frags
// (plain C++ loads -> compiler-counted lgkmcnt), MFMA cluster w/ setprio,
// vmcnt(0)+lgkmcnt(0), s_barrier. Race-free: reads target cur, staging
// targets other; cur overwritten only after the barrier both counters
// drained at. XOR swizzle on both sides (rule 21) -> 0 bank conflicts.

// swizzled fragment read: row r, k-col kc (element units) from [rows]x64 tile
#define FRAG(BUF, r, kc) \
    (*reinterpret_cast<const bf16x8*>(&(BUF)[(size_t)(r) * 64 + (((((kc) >> 3) ^ ((r) & 7)) << 3))]))

template <int BN, bool ADD_BIAS, bool SCALE, typename OutT>
__global__ __launch_bounds__(512, 2) void gemm_bt(const unsigned short* __restrict__ A,
                                                  const unsigned short* __restrict__ Bm,
                                                  const float* __restrict__ bias,
                                                  const float* __restrict__ scale_p,
                                                  OutT* __restrict__ C, int M, int N, int Kd) {
    constexpr int NB = BN / 64;        // B-frags per wave
    constexpr int WCOL = BN / 4;       // wave column extent
    __shared__ unsigned short As0[256 * 64];
    __shared__ unsigned short Bs0[BN * 64];
    __shared__ unsigned short As1[256 * 64];
    __shared__ unsigned short Bs1[BN * 64];

    const int tid = threadIdx.x;
    const int w = tid >> 6, l = tid & 63;
    const int m0 = blockIdx.x * 256;
    const int n0 = blockIdx.y * BN;
    const int wm = w >> 2, wn = w & 3;         // 2 x 4 wave grid
    const int lr = l & 15, lk = (l >> 4) * 8;
    const int nt = Kd >> 6;                    // 16 (GEMM1) / 8 (GEMM2), even

    // staging geometry: group G covers rows G*64+srow, 8 slots of 8 elems
    const int srow = tid >> 3;                 // 0..63
    const int sslot = tid & 7;
    const int wbase = tid & ~63;
    const int acol = (sslot ^ (srow & 7)) << 3;   // swizzled elem col in row

    f32x4 acc[8][NB];
#pragma unroll
    for (int mi = 0; mi < 8; ++mi)
#pragma unroll
        for (int ni = 0; ni < NB; ++ni) acc[mi][ni] = (f32x4){0.f, 0.f, 0.f, 0.f};

#define STAGE_ALL(PA, PB, K0)                                                         \
    {                                                                                 \
        _Pragma("unroll") for (int g = 0; g < 4; ++g) {                               \
            int row = g * 64 + srow;                                                  \
            gload_lds16(A + (size_t)(m0 + row) * Kd + (K0) + acol,                    \
                        (PA) + ((g * 512 + wbase)) * 8);                              \
        }                                                                             \
        _Pragma("unroll") for (int g = 0; g < NB; ++g) {                              \
            int row = g * 64 + srow;                                                  \
            gload_lds16(Bm + (size_t)(n0 + row) * Kd + (K0) + acol,                   \
                        (PB) + ((g * 512 + wbase)) * 8);                              \
        }                                                                             \
    }

#define TILE_STEP(T, CA, CB, PA, PB)                                                  \
    {                                                                                 \
        if ((T) + 1 < nt) STAGE_ALL(PA, PB, ((T) + 1) * 64);                          \
        _Pragma("unroll") for (int kkI = 0; kkI < 2; ++kkI) {                         \
            const int kk = kkI * 32;                                                  \
            bf16x8 af[8], bfr[NB];                                                    \
            _Pragma("unroll") for (int f = 0; f < 8; ++f) {                           \
                int ar = wm * 128 + f * 16 + lr;                                      \
                af[f] = FRAG(CA, ar, kk + lk);                                        \
            }                                                                         \
            _Pragma("unroll") for (int f = 0; f < NB; ++f) {                          \
                int br = wn * WCOL + f * 16 + lr;                                     \
                bfr[f] = FRAG(CB, br, kk + lk);                                       \
            }                                                                         \
            __builtin_amdgcn_s_setprio(1);                                            \
            _Pragma("unroll") for (int mi = 0; mi < 8; ++mi)                          \
                _Pragma("unroll") for (int ni = 0; ni < NB; ++ni)                     \
                    acc[mi][ni] = __builtin_amdgcn_mfma_f32_16x16x32_bf16(            \
                        af[mi], bfr[ni], acc[mi][ni], 0, 0, 0);                       \
            __builtin_amdgcn_s_setprio(0);                                            \
        }                                                                             \
        asm volatile("s_waitcnt vmcnt(0) lgkmcnt(0)" ::: "memory");                   \
        __builtin_amdgcn_s_barrier();                                                 \
    }

    // prologue: stage tile 0 into dbuf0, drain, barrier
    STAGE_ALL(As0, Bs0, 0);
    asm volatile("s_waitcnt vmcnt(0)" ::: "memory");
    __builtin_amdgcn_s_barrier();

    for (int t = 0; t < nt; t += 2) {
        TILE_STEP(t, As0, Bs0, As1, Bs1);
        TILE_STEP(t + 1, As1, Bs1, As0, Bs0);
    }

    float sc = SCALE ? *scale_p : 1.0f;
#pragma unroll
    for (int mi = 0; mi < 8; ++mi) {
        int row = m0 + wm * 128 + mi * 16 + (l >> 4) * 4;
#pragma unroll
        for (int ni = 0; ni < NB; ++ni) {
            int col = n0 + wn * WCOL + ni * 16 + lr;
            float bv = ADD_BIAS ? bias[col] : 0.0f;
#pragma unroll
            for (int j = 0; j < 4; ++j) {
                float v = acc[mi][ni][j] + bv;
                if (SCALE) v *= sc;
                C[(size_t)(row + j) * N + col] = (OutT)v;
            }
        }
    }
#undef STAGE_ALL
#undef TILE_STEP
}

// ---------------- per-step oscillator math (fp16 raw) ----------------
struct Step {
    float alpha, dr, di, cs, sn, g, beta;
};
template <bool FULL>
static __device__ __forceinline__ Step compute_step(const _Float16* __restrict__ p, float pos) {
    Step s;
    float a_raw = (float)p[0];
    float o_raw = (float)p[K_];
    float phi   = (float)p[2 * K_];
    float al    = (float)p[3 * K_];
    float A     = AMP_MAX * sigm(a_raw);
    float omega = softplusf_(o_raw);
    float alpha = sigm(al + GATE_BIAS);
    float angle = omega * pos + phi;
    float sn, cs;
    __sincosf(angle, &sn, &cs);
    float oma = 1.0f - alpha;
    s.alpha = alpha;
    s.dr = oma * A * cs;
    s.di = oma * A * sn;
    s.cs = cs;
    s.sn = sn;
    if (FULL) {
        s.g    = sigm((float)p[4 * K_]);
        s.beta = sigm((float)p[5 * K_]);
    }
    return s;
}

// ---------------- scan stage 1: chunk + sub-chunk summaries ----------------
// grid: (chunk=16, kgroup=16, b=4); block: 256 = 16 channels x 16 sub-chunks of 16 steps
__global__ __launch_bounds__(256) void scan_sum_kernel(const _Float16* __restrict__ raw,
                                                       float* __restrict__ sA,
                                                       float* __restrict__ sR,
                                                       float* __restrict__ sI,
                                                       float* __restrict__ subA,
                                                       float* __restrict__ subR,
                                                       float* __restrict__ subI) {
    const int tid = threadIdx.x;
    const int c = tid & 15, t = tid >> 4;
    const int chunk = blockIdx.x, kg = blockIdx.y, b = blockIdx.z;
    const int k = kg * 16 + c;
    const int n0 = chunk * 256 + t * 16;
    const _Float16* base = raw + (size_t)(b * N_ + n0) * P_ + k;

    float aP = 1.0f, rR = 0.0f, rI = 0.0f;
#pragma unroll
    for (int j = 0; j < 16; ++j) {
        Step s = compute_step<false>(base + (size_t)j * P_, __logf((float)(n0 + j + 1)));
        aP *= s.alpha;
        rR = s.alpha * rR + s.dr;
        rI = s.alpha * rI + s.di;
    }
    // sub-chunk summary -> global (consumed by scan_apply instead of recompute)
    const int chan = b * K_ + kg * 16 + c;
    const int sidx = (chunk * 16 + t) * 1024 + chan;
    subA[sidx] = aP;
    subR[sidx] = rR;
    subI[sidx] = rI;

    __shared__ float lA[256], lR[256], lI[256];
    lA[c * 16 + t] = aP;
    lR[c * 16 + t] = rR;
    lI[c * 16 + t] = rI;
    __syncthreads();
    if (tid < 16) {
        float a = 1.0f, r = 0.0f, im = 0.0f;
        for (int tt = 0; tt < 16; ++tt) {
            float at = lA[tid * 16 + tt];
            r  = at * r  + lR[tid * 16 + tt];
            im = at * im + lI[tid * 16 + tt];
            a *= at;
        }
        int chanw = b * K_ + kg * 16 + tid;
        sA[chunk * 1024 + chanw] = a;
        sR[chunk * 1024 + chanw] = r;
        sI[chunk * 1024 + chanw] = im;
    }
}

// ---------------- scan stage 2: apply + postprocess -> rho (bf16) ----------------
__global__ __launch_bounds__(256) void scan_apply_kernel(const _Float16* __restrict__ raw,
                                                         const float* __restrict__ sA,
                                                         const float* __restrict__ sR,
                                                         const float* __restrict__ sI,
                                                         const float* __restrict__ subA,
                                                         const float* __restrict__ subR,
                                                         const float* __restrict__ subI,
                                                         unsigned short* __restrict__ rho) {
    const int tid = threadIdx.x;
    const int c = tid & 15, t = tid >> 4;
    const int chunk = blockIdx.x, kg = blockIdx.y, b = blockIdx.z;
    const int k = kg * 16 + c;
    const int n0 = chunk * 256 + t * 16;
    const _Float16* base = raw + (size_t)(b * N_ + n0) * P_ + k;

    // chunk-prefix (exclusive) for channel handled by lanes tid<16
    float pR = 0.0f, pI = 0.0f;
    if (tid < 16) {
        int chan = b * K_ + kg * 16 + tid;
        for (int ch = 0; ch < chunk; ++ch) {
            float a = sA[ch * 1024 + chan];
            pR = a * pR + sR[ch * 1024 + chan];
            pI = a * pI + sI[ch * 1024 + chan];
        }
    }
    // sub-chunk summaries from scan_sum (replaces recompute pass)
    __shared__ float lA[256], lR[256], lI[256], pTR[256], pTI[256];
    {
        const int chan = b * K_ + kg * 16 + c;
        const int sidx = (chunk * 16 + t) * 1024 + chan;
        lA[c * 16 + t] = subA[sidx];
        lR[c * 16 + t] = subR[sidx];
        lI[c * 16 + t] = subI[sidx];
    }
    __syncthreads();
    if (tid < 16) {
        float r = pR, im = pI;
        for (int tt = 0; tt < 16; ++tt) {
            pTR[tid * 16 + tt] = r;
            pTI[tid * 16 + tt] = im;
            float at = lA[tid * 16 + tt];
            r  = at * r  + lR[tid * 16 + tt];
            im = at * im + lI[tid * 16 + tt];
        }
    }
    __syncthreads();
    // seeded walk + postprocess
    float r = pTR[c * 16 + t], im = pTI[c * 16 + t];
    unsigned short* orow = rho + (size_t)(b * N_ + n0) * DK2_ + k;
#pragma unroll
    for (int j = 0; j < 16; ++j) {
        Step s = compute_step<true>(base + (size_t)j * P_, __logf((float)(n0 + j + 1)));
        r  = s.alpha * r  + s.dr;
        im = s.alpha * im + s.di;
        float readout = r * s.cs + im * s.sn;
        float r2 = r  - s.beta * readout * s.cs;
        float i3 = im - s.beta * readout * s.sn;
        float mod = __fsqrt_rn(r2 * r2 + i3 * i3 + 1e-8f);
        float scl = fmaxf(mod, 1.0f);
        float inv = 1.0f / scl;
        float rr = r2 * inv, ri = i3 * inv;
        float rho_re = rr * s.cs + ri * s.sn;
        float rho_im = -rr * s.sn + ri * s.cs;
        orow[(size_t)j * DK2_]      = f2bf(s.g * rho_re);
        orow[(size_t)j * DK2_ + K_] = f2bf(s.g * rho_im);
    }
}

extern "C" void kernel_launch(void* const* d_in, const int* in_sizes, int n_in,
                              void* d_out, int out_size, void* d_ws, size_t ws_size,
                              hipStream_t stream) {
    const float* x  = (const float*)d_in[0];
    const float* Wp = (const float*)d_in[1];
    const float* bp = (const float*)d_in[2];
    const float* Wr = (const float*)d_in[3];
    const float* rs = (const float*)d_in[4];
    float* out = (float*)d_out;
    char* ws = (char*)d_ws;

    // workspace layout (bytes)
    _Float16* raw = (_Float16*)ws;                               // 50,331,648
    unsigned short* xb  = (unsigned short*)(ws + 100663296);     // 33,554,432
    unsigned short* wpb = (unsigned short*)(ws + 134217728);     // 3,145,728 (dead after GEMM1)
    unsigned short* wrb = (unsigned short*)(ws + 137363456);     // 1,048,576
    float* sA = (float*)(ws + 138412032);                        // 65,536
    float* sR = (float*)(ws + 138477568);                        // 65,536
    float* sI = (float*)(ws + 138543104);                        // 65,536
    unsigned short* rho = xb;            // alias: x_bf16 dead after GEMM1
    float* subA = (float*)(ws + 134217728);                      // alias wpb: 1 MB
    float* subR = (float*)(ws + 135266304);                      // 1 MB
    float* subI = (float*)(ws + 136314880);                      // 1 MB (ends at wrb)

    // all three converts, one launch: x (4,194,304 f4) + Wp (393,216) + Wr (131,072)
    cvt3_kernel<<<(4194304 + 393216 + 131072 + 255) / 256, 256, 0, stream>>>(
        x, xb, M_ * D_ / 4, Wp, wpb, P_ * D_ / 4, Wr, wrb);

    gemm_bt<192, true, false, _Float16><<<dim3(M_ / 256, P_ / 192), 512, 0, stream>>>(
        xb, wpb, bp, nullptr, raw, M_, P_, D_);

    scan_sum_kernel<<<dim3(16, 16, 4), 256, 0, stream>>>(raw, sA, sR, sI, subA, subR, subI);
    scan_apply_kernel<<<dim3(16, 16, 4), 256, 0, stream>>>(raw, sA, sR, sI, subA, subR, subI, rho);

    gemm_bt<256, false, true, float><<<dim3(M_ / 256, D_ / 256), 512, 0, stream>>>(
        rho, wrb, nullptr, rs, out, M_, D_, DK2_);
}